// Round 5
// baseline (2408.016 us; speedup 1.0000x reference)
//
#include <hip/hip_runtime.h>
#include <hip/hip_bf16.h>

// ---------------------------------------------------------------------------
// VQ-VAE forward, fp32. NCHW.
// R5: register-tiled convs — P=2 pixels x CPT=32 cout per thread, weights
// staged in LDS (chunked, broadcast ds_read_b128). R4's 67% VALUBusy at 33%
// FMA fraction pointed at per-lane global weight loads + addr VALU bloat.
// FMA accumulation order per output is IDENTICAL to R4 (ci asc, kk asc) —
// required: VQ argmin flips on 1-ulp changes (R3 failure).
// ---------------------------------------------------------------------------

// dst[(ci*KK+kk)*COUT+co] = src[(co*CIN+ci)*KK+kk]
__global__ __launch_bounds__(256) void repack_w(
    const float* __restrict__ src, float* __restrict__ dst,
    int COUT, int CIN, int KK)
{
    const int n = COUT * CIN * KK;
    const int idx = blockIdx.x * 256 + threadIdx.x;
    if (idx >= n) return;
    const int co = idx % COUT;
    const int t  = idx / COUT;
    const int kk = t % KK;
    const int ci = t / KK;
    dst[idx] = src[(co * CIN + ci) * KK + kk];
}

// t1 weights (64,32,4,4) [ci][co][kh][kw] -> dst[par][ci][tap][co]
__global__ __launch_bounds__(256) void repack_t1(
    const float* __restrict__ src, float* __restrict__ dst)
{
    const int idx = blockIdx.x * 256 + threadIdx.x;
    if (idx >= 32768) return;
    const int co  = idx & 31;
    const int tap = (idx >> 5) & 3;
    const int ci  = (idx >> 7) & 63;
    const int par = idx >> 13;
    const int pr = par >> 1, pc = par & 1;
    const int ta = tap >> 1, tb = tap & 1;
    const int kh = (1 - pr) + 2 * ta, kw = (1 - pc) + 2 * tb;
    dst[idx] = src[((ci * 32 + co) * 4 + kh) * 4 + kw];
}

// Register-tiled direct conv: P pixels (along ow) x CPT cout per thread.
// Weights staged in LDS per 16-ci chunk; inner loop: taps from global,
// weights via broadcast float4 LDS reads, FMA order = (ci asc, kk asc).
template<int CIN, int CTOT, int CPT, int K, int S, int PAD, int P,
         bool RELU_IN, bool HAS_BIAS, bool RESID, bool RELU_OUT>
__global__ __launch_bounds__(256) void conv_tiled(
    const float* __restrict__ in, const float* __restrict__ wr,
    const float* __restrict__ bias, const float* __restrict__ resid,
    float* __restrict__ out,
    int B, int H, int W, int OH, int OW)
{
    constexpr int KK = K * K;
    constexpr int NC = (P - 1) * S + K;     // tap columns per thread
    constexpr int CI_CHUNK = (CIN < 16) ? CIN : 16;
    constexpr int WELE = CI_CHUNK * KK * CPT;
    __shared__ __align__(16) float lds_w[WELE];

    const int lanes = OW / P;
    const int rows  = 256 / lanes;
    const int tx = threadIdx.x % lanes;
    const int ty = threadIdx.x / lanes;
    const int gr = blockIdx.x * rows + ty;   // row index within B*OH
    const int oh = gr % OH;
    const int b  = gr / OH;
    const int ow0 = tx * P;
    const int co0 = blockIdx.y * CPT;

    float acc[CPT * P];
#pragma unroll
    for (int c = 0; c < CPT; c++) {
        const float bz = HAS_BIAS ? bias[co0 + c] : 0.0f;
#pragma unroll
        for (int p = 0; p < P; p++) acc[c * P + p] = bz;
    }

    const float* __restrict__ inb = in + (size_t)b * CIN * H * W;
    const int colbase = ow0 * S - PAD;
    const int rowbase = oh * S - PAD;

    for (int ci0 = 0; ci0 < CIN; ci0 += CI_CHUNK) {
        __syncthreads();
        for (int idx = threadIdx.x; idx < WELE; idx += 256) {
            const int c  = idx % CPT;
            const int t  = idx / CPT;
            const int kk = t % KK;
            const int cl = t / KK;
            lds_w[idx] = wr[((size_t)(ci0 + cl) * KK + kk) * CTOT + co0 + c];
        }
        __syncthreads();

#pragma unroll 2
        for (int cl = 0; cl < CI_CHUNK; cl++) {
            const float* __restrict__ inc = inb + (size_t)(ci0 + cl) * H * W;
            float v[K][NC];
#pragma unroll
            for (int kh = 0; kh < K; kh++) {
                const int ih = rowbase + kh;
                const bool rok = (ih >= 0) && (ih < H);
#pragma unroll
                for (int j = 0; j < NC; j++) {
                    const int col = colbase + j;
                    const bool ok = rok && (col >= 0) && (col < W);
                    float t = ok ? inc[(size_t)ih * W + col] : 0.0f;
                    if (RELU_IN) t = fmaxf(t, 0.0f);
                    v[kh][j] = t;
                }
            }
            const float4* __restrict__ w4 =
                (const float4*)(lds_w + (size_t)cl * KK * CPT);
#pragma unroll
            for (int kh = 0; kh < K; kh++) {
#pragma unroll
                for (int kw = 0; kw < K; kw++) {
                    const int kk = kh * K + kw;
#pragma unroll
                    for (int c4 = 0; c4 < CPT / 4; c4++) {
                        const float4 wv = w4[kk * (CPT / 4) + c4];
#pragma unroll
                        for (int p = 0; p < P; p++) {
                            const float vx = v[kh][kw + p * S];
                            acc[(c4 * 4 + 0) * P + p] = fmaf(vx, wv.x, acc[(c4 * 4 + 0) * P + p]);
                            acc[(c4 * 4 + 1) * P + p] = fmaf(vx, wv.y, acc[(c4 * 4 + 1) * P + p]);
                            acc[(c4 * 4 + 2) * P + p] = fmaf(vx, wv.z, acc[(c4 * 4 + 2) * P + p]);
                            acc[(c4 * 4 + 3) * P + p] = fmaf(vx, wv.w, acc[(c4 * 4 + 3) * P + p]);
                        }
                    }
                }
            }
        }
    }

    const size_t obase = (((size_t)b * CTOT + co0) * OH + oh) * OW + ow0;
    const size_t cstride = (size_t)OH * OW;
#pragma unroll
    for (int c = 0; c < CPT; c++) {
#pragma unroll
        for (int p = 0; p < P; p++) {
            float r = acc[c * P + p];
            if (RESID) r += resid[obase + (size_t)c * cstride + p];
            if (RELU_OUT) r = fmaxf(r, 0.0f);
            out[obase + (size_t)c * cstride + p] = r;
        }
    }
}

// Register-tiled transposed conv 4x4 s2 p1 (t1): parity blocks, P=2 pixels,
// weights [par][ci][tap][co] staged in LDS. ih(ta) = i+pr-ta; per-pixel col
// index into v[ta][*] is p - tb + 1.
template<int CIN, int COUT, bool RELU_OUT>
__global__ __launch_bounds__(256) void convt_tiled(
    const float* __restrict__ in, const float* __restrict__ wr,
    const float* __restrict__ bias, float* __restrict__ out,
    int B, int IH, int IW)
{
    constexpr int CI_CHUNK = 16;
    constexpr int WELE = CI_CHUNK * 4 * COUT;
    __shared__ __align__(16) float lds_w[WELE];

    const int OH = IH * 2, OW = IW * 2;
    const int j0 = (threadIdx.x & 31) * 2;          // half-res col base, P=2
    const int i  = blockIdx.x * 8 + (threadIdx.x >> 5);
    const int par = blockIdx.y;
    const int pr = par >> 1, pc = par & 1;
    const int b = blockIdx.z;

    float acc[COUT * 2];
#pragma unroll
    for (int c = 0; c < COUT; c++) {
        const float bz = bias[c];
        acc[c * 2 + 0] = bz;
        acc[c * 2 + 1] = bz;
    }

    const float* __restrict__ inb = in + (size_t)b * CIN * IH * IW;
    const float* __restrict__ wpar = wr + (size_t)par * CIN * 4 * COUT;

    for (int ci0 = 0; ci0 < CIN; ci0 += CI_CHUNK) {
        __syncthreads();
        for (int idx = threadIdx.x; idx < WELE; idx += 256)
            lds_w[idx] = wpar[(size_t)ci0 * 4 * COUT + idx];
        __syncthreads();

#pragma unroll 2
        for (int cl = 0; cl < CI_CHUNK; cl++) {
            const float* __restrict__ inc = inb + (size_t)(ci0 + cl) * IH * IW;
            float v[2][3];
#pragma unroll
            for (int ta = 0; ta < 2; ta++) {
                const int ih = i + pr - ta;
                const bool rok = (ih >= 0) && (ih < IH);
#pragma unroll
                for (int m = 0; m < 3; m++) {
                    const int col = j0 + pc - 1 + m;
                    const bool ok = rok && (col >= 0) && (col < IW);
                    v[ta][m] = ok ? inc[(size_t)ih * IW + col] : 0.0f;
                }
            }
            const float4* __restrict__ w4 =
                (const float4*)(lds_w + (size_t)cl * 4 * COUT);
#pragma unroll
            for (int ta = 0; ta < 2; ta++) {
#pragma unroll
                for (int tb = 0; tb < 2; tb++) {
                    const int tap = ta * 2 + tb;
#pragma unroll
                    for (int c4 = 0; c4 < COUT / 4; c4++) {
                        const float4 wv = w4[tap * (COUT / 4) + c4];
#pragma unroll
                        for (int p = 0; p < 2; p++) {
                            const float vx = v[ta][p - tb + 1];
                            acc[(c4 * 4 + 0) * 2 + p] = fmaf(vx, wv.x, acc[(c4 * 4 + 0) * 2 + p]);
                            acc[(c4 * 4 + 1) * 2 + p] = fmaf(vx, wv.y, acc[(c4 * 4 + 1) * 2 + p]);
                            acc[(c4 * 4 + 2) * 2 + p] = fmaf(vx, wv.z, acc[(c4 * 4 + 2) * 2 + p]);
                            acc[(c4 * 4 + 3) * 2 + p] = fmaf(vx, wv.w, acc[(c4 * 4 + 3) * 2 + p]);
                        }
                    }
                }
            }
        }
    }

    const int oh = 2 * i + pr;
    const size_t cstride = (size_t)OH * OW;
    const size_t obase = (((size_t)b * COUT) * OH + oh) * OW;
#pragma unroll
    for (int c = 0; c < COUT; c++) {
#pragma unroll
        for (int p = 0; p < 2; p++) {
            float r = acc[c * 2 + p];
            if (RELU_OUT) r = fmaxf(r, 0.0f);
            out[obase + (size_t)c * cstride + 2 * (j0 + p) + pc] = r;
        }
    }
}

// Final transposed conv (32 -> 1): one thread per half-res position computes
// the 2x2 output quad from its 3x3 neighborhood.
__global__ __launch_bounds__(256) void convt2_quad(
    const float* __restrict__ in,  // (B,32,128,128)
    const float* __restrict__ w,   // (32,1,4,4)
    const float* __restrict__ bias,
    float* __restrict__ out,       // (B,1,256,256)
    int B)
{
    const int IH = 128, IW = 128, CIN = 32, OW = 256;
    const int j = threadIdx.x & 127;
    const int i = (blockIdx.x << 1) + (threadIdx.x >> 7);
    const int b = blockIdx.y;

    const float* __restrict__ inb = in + (size_t)b * CIN * IH * IW;
    const float bz = bias[0];
    float a00 = bz, a01 = bz, a10 = bz, a11 = bz;

    const bool okm = (i > 0);
    const bool okp = (i < IH - 1);
    const bool olm = (j > 0);
    const bool olp = (j < IW - 1);

#pragma unroll 4
    for (int ci = 0; ci < CIN; ci++) {
        const float* __restrict__ p = inb + ((size_t)ci * IH + i) * IW + j;
        const float* __restrict__ wp = w + ci * 16;
        const float vmm = (okm && olm) ? p[-IW - 1] : 0.f;
        const float vm0 = okm ? p[-IW] : 0.f;
        const float vmp = (okm && olp) ? p[-IW + 1] : 0.f;
        const float v0m = olm ? p[-1] : 0.f;
        const float v00 = p[0];
        const float v0p = olp ? p[1] : 0.f;
        const float vpm = (okp && olm) ? p[IW - 1] : 0.f;
        const float vp0 = okp ? p[IW] : 0.f;
        const float vpp = (okp && olp) ? p[IW + 1] : 0.f;
        a00 = fmaf(v00, wp[1 * 4 + 1], a00);
        a00 = fmaf(v0m, wp[1 * 4 + 3], a00);
        a00 = fmaf(vm0, wp[3 * 4 + 1], a00);
        a00 = fmaf(vmm, wp[3 * 4 + 3], a00);
        a01 = fmaf(v0p, wp[1 * 4 + 0], a01);
        a01 = fmaf(v00, wp[1 * 4 + 2], a01);
        a01 = fmaf(vmp, wp[3 * 4 + 0], a01);
        a01 = fmaf(vm0, wp[3 * 4 + 2], a01);
        a10 = fmaf(vp0, wp[0 * 4 + 1], a10);
        a10 = fmaf(vpm, wp[0 * 4 + 3], a10);
        a10 = fmaf(v00, wp[2 * 4 + 1], a10);
        a10 = fmaf(v0m, wp[2 * 4 + 3], a10);
        a11 = fmaf(vpp, wp[0 * 4 + 0], a11);
        a11 = fmaf(vp0, wp[0 * 4 + 2], a11);
        a11 = fmaf(v0p, wp[2 * 4 + 0], a11);
        a11 = fmaf(v00, wp[2 * 4 + 2], a11);
    }

    float* __restrict__ outb = out + (size_t)b * 256 * 256;
    ((float2*)(outb + (size_t)(2 * i) * OW))[j] = make_float2(a00, a01);
    ((float2*)(outb + (size_t)(2 * i + 1) * OW))[j] = make_float2(a10, a11);
}

// Vector quantization. Codebook staged through LDS in 128-row chunks (same
// values, same sequential FMA chain order -> same rounding as R4 -> same
// argmin). DO NOT restructure the dot-product chain (R3 failure).
__global__ __launch_bounds__(256) void vq_kernel(
    const float* __restrict__ h,   // (B,64,HW)
    const float* __restrict__ cb,  // (512,64)
    float* __restrict__ q,         // (B,64,HW)
    int B, int HW)
{
    __shared__ float ee[512];
    __shared__ __align__(16) float cbl[128 * 64];

    for (int k = threadIdx.x; k < 512; k += 256) {
        const float* __restrict__ cp = cb + (size_t)k * 64;
        float s = 0.0f;
#pragma unroll
        for (int i = 0; i < 64; i++) s = fmaf(cp[i], cp[i], s);
        ee[k] = s;
    }

    const int gid = blockIdx.x * 256 + threadIdx.x;  // grid exact: B*HW/256
    const int hw = gid % HW;
    const int b  = gid / HW;

    const float* __restrict__ hp = h + (size_t)b * 64 * HW + hw;
    float x[64];
#pragma unroll
    for (int i = 0; i < 64; i++) x[i] = hp[(size_t)i * HW];
    float xx = 0.0f;
#pragma unroll
    for (int i = 0; i < 64; i++) xx = fmaf(x[i], x[i], xx);

    float best = 3.402823466e+38f;
    int bidx = 0;
    for (int kc = 0; kc < 4; kc++) {
        __syncthreads();
        for (int idx = threadIdx.x; idx < 8192; idx += 256)
            cbl[idx] = cb[(size_t)kc * 8192 + idx];
        __syncthreads();
#pragma unroll 2
        for (int kl = 0; kl < 128; kl++) {
            const float* __restrict__ cp = cbl + kl * 64;
            float dot = 0.0f;
#pragma unroll
            for (int i = 0; i < 64; i++) dot = fmaf(x[i], cp[i], dot);
            const int k = kc * 128 + kl;
            const float d = xx - 2.0f * dot + ee[k];
            if (d < best) { best = d; bidx = k; }
        }
    }

    const float4* __restrict__ cp4 = (const float4*)(cb + (size_t)bidx * 64);
    float* __restrict__ qp = q + (size_t)b * 64 * HW + hw;
#pragma unroll
    for (int i = 0; i < 16; i++) {
        const float4 v = cp4[i];
        qp[(size_t)(4 * i + 0) * HW] = v.x;
        qp[(size_t)(4 * i + 1) * HW] = v.y;
        qp[(size_t)(4 * i + 2) * HW] = v.z;
        qp[(size_t)(4 * i + 3) * HW] = v.w;
    }
}

extern "C" void kernel_launch(void* const* d_in, const int* in_sizes, int n_in,
                              void* d_out, int out_size, void* d_ws, size_t ws_size,
                              hipStream_t stream) {
    const float* x      = (const float*)d_in[0];
    const float* w_e1   = (const float*)d_in[1];
    const float* b_e1   = (const float*)d_in[2];
    const float* w_e2   = (const float*)d_in[3];
    const float* b_e2   = (const float*)d_in[4];
    const float* w_er1a = (const float*)d_in[5];
    const float* w_er1b = (const float*)d_in[6];
    const float* w_er2a = (const float*)d_in[7];
    const float* w_er2b = (const float*)d_in[8];
    const float* w_pre  = (const float*)d_in[9];
    const float* b_pre  = (const float*)d_in[10];
    const float* cbk    = (const float*)d_in[11];
    const float* w_d1   = (const float*)d_in[12];
    const float* b_d1   = (const float*)d_in[13];
    const float* w_dr1a = (const float*)d_in[14];
    const float* w_dr1b = (const float*)d_in[15];
    const float* w_dr2a = (const float*)d_in[16];
    const float* w_dr2b = (const float*)d_in[17];
    const float* w_t1   = (const float*)d_in[18];
    const float* b_t1   = (const float*)d_in[19];
    const float* w_t2   = (const float*)d_in[20];
    const float* b_t2   = (const float*)d_in[21];
    float* out = (float*)d_out;

    float* A  = (float*)d_ws;            // (32,32,128,128) = 16777216
    float* Bb = A  + 16777216;           // (32,64,64,64)   = 8388608
    float* C  = Bb + 8388608;            // (32,32,64,64)   = 4194304
    float* D  = C  + 4194304;            // (32,64,64,64)   = 8388608
    float* WR = D  + 8388608;            // repacked weights

    float* r_e1   = WR;                  // 512
    float* r_e2   = r_e1  + 512;         // 32768
    float* r_er1a = r_e2  + 32768;       // 18432
    float* r_er1b = r_er1a + 18432;      // 2048
    float* r_er2a = r_er1b + 2048;       // 18432
    float* r_er2b = r_er2a + 18432;      // 2048
    float* r_pre  = r_er2b + 2048;       // 4096
    float* r_d1   = r_pre  + 4096;       // 36864
    float* r_dr1a = r_d1   + 36864;      // 18432
    float* r_dr1b = r_dr1a + 18432;      // 2048
    float* r_dr2a = r_dr1b + 2048;       // 18432
    float* r_dr2b = r_dr2a + 18432;      // 2048
    float* r_t1   = r_dr2b + 2048;       // 32768

    const dim3 blk(256);
    auto rb = [](int n) { return dim3((n + 255) / 256); };

    repack_w<<<rb(512),   blk, 0, stream>>>(w_e1,   r_e1,   32,  1, 16);
    repack_w<<<rb(32768), blk, 0, stream>>>(w_e2,   r_e2,   64, 32, 16);
    repack_w<<<rb(18432), blk, 0, stream>>>(w_er1a, r_er1a, 32, 64,  9);
    repack_w<<<rb(2048),  blk, 0, stream>>>(w_er1b, r_er1b, 64, 32,  1);
    repack_w<<<rb(18432), blk, 0, stream>>>(w_er2a, r_er2a, 32, 64,  9);
    repack_w<<<rb(2048),  blk, 0, stream>>>(w_er2b, r_er2b, 64, 32,  1);
    repack_w<<<rb(4096),  blk, 0, stream>>>(w_pre,  r_pre,  64, 64,  1);
    repack_w<<<rb(36864), blk, 0, stream>>>(w_d1,   r_d1,   64, 64,  9);
    repack_w<<<rb(18432), blk, 0, stream>>>(w_dr1a, r_dr1a, 32, 64,  9);
    repack_w<<<rb(2048),  blk, 0, stream>>>(w_dr1b, r_dr1b, 64, 32,  1);
    repack_w<<<rb(18432), blk, 0, stream>>>(w_dr2a, r_dr2a, 32, 64,  9);
    repack_w<<<rb(2048),  blk, 0, stream>>>(w_dr2b, r_dr2b, 64, 32,  1);
    repack_t1<<<rb(32768), blk, 0, stream>>>(w_t1, r_t1);

    // Encoder
    // e1: OW=128, P=2 -> lanes 64, rows 4 -> grid.x = 32*128/4 = 1024
    conv_tiled<1, 32, 32, 4, 2, 1, 2, false, true, false, true>
        <<<dim3(1024, 1), blk, 0, stream>>>(
            x, r_e1, b_e1, nullptr, A, 32, 256, 256, 128, 128);
    // e2: OW=64 -> lanes 32, rows 8 -> grid.x = 32*64/8 = 256
    conv_tiled<32, 64, 32, 4, 2, 1, 2, false, true, false, false>
        <<<dim3(256, 2), blk, 0, stream>>>(
            A, r_e2, b_e2, nullptr, Bb, 32, 128, 128, 64, 64);
    conv_tiled<64, 32, 32, 3, 1, 1, 2, true, false, false, false>
        <<<dim3(256, 1), blk, 0, stream>>>(
            Bb, r_er1a, nullptr, nullptr, C, 32, 64, 64, 64, 64);
    conv_tiled<32, 64, 32, 1, 1, 0, 2, true, false, true, false>
        <<<dim3(256, 2), blk, 0, stream>>>(
            C, r_er1b, nullptr, Bb, Bb, 32, 64, 64, 64, 64);
    conv_tiled<64, 32, 32, 3, 1, 1, 2, true, false, false, false>
        <<<dim3(256, 1), blk, 0, stream>>>(
            Bb, r_er2a, nullptr, nullptr, C, 32, 64, 64, 64, 64);
    conv_tiled<32, 64, 32, 1, 1, 0, 2, true, false, true, false>
        <<<dim3(256, 2), blk, 0, stream>>>(
            C, r_er2b, nullptr, Bb, Bb, 32, 64, 64, 64, 64);
    conv_tiled<64, 64, 32, 1, 1, 0, 2, false, true, false, false>
        <<<dim3(256, 2), blk, 0, stream>>>(
            Bb, r_pre, b_pre, nullptr, D, 32, 64, 64, 64, 64);
    // VQ
    vq_kernel<<<dim3(512), blk, 0, stream>>>(D, cbk, Bb, 32, 4096);
    // Decoder
    conv_tiled<64, 64, 32, 3, 1, 1, 2, false, true, false, false>
        <<<dim3(256, 2), blk, 0, stream>>>(
            Bb, r_d1, b_d1, nullptr, D, 32, 64, 64, 64, 64);
    conv_tiled<64, 32, 32, 3, 1, 1, 2, true, false, false, false>
        <<<dim3(256, 1), blk, 0, stream>>>(
            D, r_dr1a, nullptr, nullptr, C, 32, 64, 64, 64, 64);
    conv_tiled<32, 64, 32, 1, 1, 0, 2, true, false, true, false>
        <<<dim3(256, 2), blk, 0, stream>>>(
            C, r_dr1b, nullptr, D, D, 32, 64, 64, 64, 64);
    conv_tiled<64, 32, 32, 3, 1, 1, 2, true, false, false, false>
        <<<dim3(256, 1), blk, 0, stream>>>(
            D, r_dr2a, nullptr, nullptr, C, 32, 64, 64, 64, 64);
    conv_tiled<32, 64, 32, 1, 1, 0, 2, true, false, true, false>
        <<<dim3(256, 2), blk, 0, stream>>>(
            C, r_dr2b, nullptr, D, D, 32, 64, 64, 64, 64);
    // t1: grid (64/8=8, 4 parities, 32 batch)
    convt_tiled<64, 32, true>
        <<<dim3(8, 4, 32), blk, 0, stream>>>(
            D, r_t1, b_t1, A, 32, 64, 64);
    // t2
    convt2_quad<<<dim3(64, 32), blk, 0, stream>>>(A, w_t2, b_t2, out, 32);
}

// Round 6
// 2000.251 us; speedup vs baseline: 1.2039x; 1.2039x over previous
//
#include <hip/hip_runtime.h>
#include <hip/hip_bf16.h>

// ---------------------------------------------------------------------------
// VQ-VAE forward, fp32. NCHW.
// R6: GEMM-form convs. Lane dim = 64 pixel-threads (A from LDS, stride-1
// ds_read_b128); weight indices wave-uniform (readfirstlane'd cout group) ->
// SGPR s_load, FMA takes weight as the scalar operand. Thread tile =
// CPTHD couts x 4 pixels (acc <= 64 VGPR; R5 died of 256-VGPR spills).
// Per-output FMA order = (ci asc, kk asc) with bias init — BIT-IDENTICAL to
// R4 everywhere, so the VQ argmin cannot flip (R3 lesson). vq/t2 kernels are
// the validated ones, unchanged.
// ---------------------------------------------------------------------------

// dst[(ci*KK+kk)*COUT+co] = src[(co*CIN+ci)*KK+kk]
__global__ __launch_bounds__(256) void repack_w(
    const float* __restrict__ src, float* __restrict__ dst,
    int COUT, int CIN, int KK)
{
    const int n = COUT * CIN * KK;
    const int idx = blockIdx.x * 256 + threadIdx.x;
    if (idx >= n) return;
    const int co = idx % COUT;
    const int t  = idx / COUT;
    const int kk = t % KK;
    const int ci = t / KK;
    dst[idx] = src[(co * CIN + ci) * KK + kk];
}

// t1 weights (64,32,4,4) [ci][co][kh][kw] -> dst[par][ci*4+tap][co]
// par=pr*2+pc, tap=ta*2+tb, kh=(1-pr)+2*ta, kw=(1-pc)+2*tb
__global__ __launch_bounds__(256) void repack_t1(
    const float* __restrict__ src, float* __restrict__ dst)
{
    const int idx = blockIdx.x * 256 + threadIdx.x;
    if (idx >= 32768) return;
    const int co  = idx & 31;
    const int tap = (idx >> 5) & 3;
    const int ci  = (idx >> 7) & 63;
    const int par = idx >> 13;
    const int pr = par >> 1, pc = par & 1;
    const int ta = tap >> 1, tb = tap & 1;
    const int kh = (1 - pr) + 2 * ta, kw = (1 - pc) + 2 * tb;
    dst[idx] = src[((ci * 32 + co) * 4 + kh) * 4 + kw];
}

// GEMM-form conv. Block: CTOT couts x 256 pixels. 64 pixel-threads (lane),
// 4 cout-groups (wave index, scalarized). Thread: CPTHD couts x 4 pixels.
// K-loop over (ci,kk) ascending in chunks of 8 staged into LDS (im2col).
template<int CTOT, int CPTHD, int CIN, int K, int S, int PAD,
         bool RELU_IN, bool HAS_BIAS, bool RESID, bool RELU_OUT>
__global__ __launch_bounds__(256) void conv_gemm(
    const float* __restrict__ in, const float* __restrict__ wr,
    const float* __restrict__ bias, const float* __restrict__ resid,
    float* __restrict__ out,
    int H, int W, int OH, int OW)
{
    constexpr int KK = K * K;
    constexpr int KTOT = CIN * KK;      // divisible by 8 for all layers here
    constexpr int NT = 256;
    constexpr int KC = 8;
    __shared__ __align__(16) float As[KC * NT];

    const int tid = threadIdx.x;
    const int tpx = tid & 63;
    const int tco = __builtin_amdgcn_readfirstlane(tid >> 6);  // 0..3, wave-uniform
    const int co0 = tco * CPTHD;

    const int ohow = OH * OW;
    // staging decode: one pixel per thread, fixed for all chunks
    const int n_st = blockIdx.x * NT + tid;
    const int b_st = n_st / ohow;
    const int hw_s = n_st % ohow;
    const int ih0 = (hw_s / OW) * S - PAD;
    const int iw0 = (hw_s % OW) * S - PAD;
    const float* __restrict__ inb = in + (size_t)b_st * CIN * H * W;

    float acc[CPTHD][4];
#pragma unroll
    for (int c = 0; c < CPTHD; c++) {
        const float bz = HAS_BIAS ? bias[co0 + c] : 0.0f;
#pragma unroll
        for (int q = 0; q < 4; q++) acc[c][q] = bz;
    }

#pragma unroll 1
    for (int k0 = 0; k0 < KTOT; k0 += KC) {
        __syncthreads();
#pragma unroll
        for (int t = 0; t < KC; t++) {
            const int k  = k0 + t;
            const int ci = k / KK;
            const int kk = k % KK;
            const int ih = ih0 + kk / K;
            const int iw = iw0 + kk % K;
            float v = 0.0f;
            if (ih >= 0 && ih < H && iw >= 0 && iw < W)
                v = inb[(size_t)ci * H * W + ih * W + iw];
            if (RELU_IN) v = fmaxf(v, 0.0f);
            As[t * NT + tid] = v;
        }
        __syncthreads();
#pragma unroll
        for (int t = 0; t < KC; t++) {
            const float4 a4 = *(const float4*)(As + t * NT + tpx * 4);
            const float* __restrict__ wk = wr + (size_t)(k0 + t) * CTOT + co0;
#pragma unroll
            for (int c = 0; c < CPTHD; c++) {
                const float w = wk[c];
                acc[c][0] = fmaf(a4.x, w, acc[c][0]);
                acc[c][1] = fmaf(a4.y, w, acc[c][1]);
                acc[c][2] = fmaf(a4.z, w, acc[c][2]);
                acc[c][3] = fmaf(a4.w, w, acc[c][3]);
            }
        }
    }

    // epilogue: pixels n0 + tpx*4 + q (4-aligned, within one b/row group)
    const int n_c  = blockIdx.x * NT + tpx * 4;
    const int b_c  = n_c / ohow;
    const int hw_c = n_c % ohow;
    float* __restrict__ op = out + (size_t)b_c * CTOT * ohow + hw_c;
    const float* __restrict__ rp =
        RESID ? (resid + (size_t)b_c * CTOT * ohow + hw_c) : nullptr;
#pragma unroll
    for (int c = 0; c < CPTHD; c++) {
        const size_t off = (size_t)(co0 + c) * ohow;
        float4 r = make_float4(acc[c][0], acc[c][1], acc[c][2], acc[c][3]);
        if (RESID) {
            const float4 rv = *(const float4*)(rp + off);
            r.x += rv.x; r.y += rv.y; r.z += rv.z; r.w += rv.w;
        }
        if (RELU_OUT) {
            r.x = fmaxf(r.x, 0.f); r.y = fmaxf(r.y, 0.f);
            r.z = fmaxf(r.z, 0.f); r.w = fmaxf(r.w, 0.f);
        }
        *(float4*)(op + off) = r;
    }
}

// GEMM-form transposed conv t1 (64 -> 32, 4x4 s2 p1), per parity class.
// N-space = B x IH x IW (half-res). K = ci*4 + tap, ascending (= R4 order).
__global__ __launch_bounds__(256) void convt_gemm(
    const float* __restrict__ in, const float* __restrict__ wr,  // [par][256][32]
    const float* __restrict__ bias, float* __restrict__ out,
    int IH, int IW)
{
    constexpr int NT = 256, KC = 8, KTOT = 256, CTOT = 32, CPTHD = 8;
    __shared__ __align__(16) float As[KC * NT];

    const int tid = threadIdx.x;
    const int tpx = tid & 63;
    const int tco = __builtin_amdgcn_readfirstlane(tid >> 6);
    const int co0 = tco * CPTHD;
    const int par = blockIdx.y;
    const int pr = par >> 1, pc = par & 1;
    const int ihiw = IH * IW;
    const int OH = IH * 2, OW = IW * 2;

    const int n_st = blockIdx.x * NT + tid;
    const int b_st = n_st / ihiw;
    const int r_s  = n_st % ihiw;
    const int i_st = r_s / IW;
    const int j_st = r_s % IW;
    const float* __restrict__ inb = in + (size_t)b_st * 64 * ihiw;

    float acc[CPTHD][4];
#pragma unroll
    for (int c = 0; c < CPTHD; c++) {
        const float bz = bias[co0 + c];
#pragma unroll
        for (int q = 0; q < 4; q++) acc[c][q] = bz;
    }

    const float* __restrict__ wpar = wr + (size_t)par * KTOT * CTOT;

#pragma unroll 1
    for (int k0 = 0; k0 < KTOT; k0 += KC) {
        __syncthreads();
#pragma unroll
        for (int t = 0; t < KC; t++) {
            const int k  = k0 + t;
            const int ci = k >> 2;
            const int ta = (k >> 1) & 1;
            const int tb = k & 1;
            const int ih = i_st + pr - ta;
            const int iw = j_st + pc - tb;
            float v = 0.0f;
            if (ih >= 0 && ih < IH && iw >= 0 && iw < IW)
                v = inb[(size_t)ci * ihiw + ih * IW + iw];
            As[t * NT + tid] = v;
        }
        __syncthreads();
#pragma unroll
        for (int t = 0; t < KC; t++) {
            const float4 a4 = *(const float4*)(As + t * NT + tpx * 4);
            const float* __restrict__ wk = wpar + (size_t)(k0 + t) * CTOT + co0;
#pragma unroll
            for (int c = 0; c < CPTHD; c++) {
                const float w = wk[c];
                acc[c][0] = fmaf(a4.x, w, acc[c][0]);
                acc[c][1] = fmaf(a4.y, w, acc[c][1]);
                acc[c][2] = fmaf(a4.z, w, acc[c][2]);
                acc[c][3] = fmaf(a4.w, w, acc[c][3]);
            }
        }
    }

    const int n_c = blockIdx.x * NT + tpx * 4;
    const int b_c = n_c / ihiw;
    const int r_c = n_c % ihiw;
    const int i_c = r_c / IW;
    const int j_c = r_c % IW;
    const int oh = 2 * i_c + pr;
    float* __restrict__ ob = out + (size_t)b_c * CTOT * OH * OW + (size_t)oh * OW;
#pragma unroll
    for (int c = 0; c < CPTHD; c++) {
        const size_t off = (size_t)(co0 + c) * OH * OW;
#pragma unroll
        for (int q = 0; q < 4; q++)
            ob[off + 2 * (j_c + q) + pc] = fmaxf(acc[c][q], 0.0f);
    }
}

// Final transposed conv (32 -> 1): one thread per half-res position computes
// the 2x2 output quad from its 3x3 neighborhood. (validated R2/R4/R5)
__global__ __launch_bounds__(256) void convt2_quad(
    const float* __restrict__ in,  // (B,32,128,128)
    const float* __restrict__ w,   // (32,1,4,4)
    const float* __restrict__ bias,
    float* __restrict__ out,       // (B,1,256,256)
    int B)
{
    const int IH = 128, IW = 128, CIN = 32, OW = 256;
    const int j = threadIdx.x & 127;
    const int i = (blockIdx.x << 1) + (threadIdx.x >> 7);
    const int b = blockIdx.y;

    const float* __restrict__ inb = in + (size_t)b * CIN * IH * IW;
    const float bz = bias[0];
    float a00 = bz, a01 = bz, a10 = bz, a11 = bz;

    const bool okm = (i > 0);
    const bool okp = (i < IH - 1);
    const bool olm = (j > 0);
    const bool olp = (j < IW - 1);

#pragma unroll 4
    for (int ci = 0; ci < CIN; ci++) {
        const float* __restrict__ p = inb + ((size_t)ci * IH + i) * IW + j;
        const float* __restrict__ wp = w + ci * 16;
        const float vmm = (okm && olm) ? p[-IW - 1] : 0.f;
        const float vm0 = okm ? p[-IW] : 0.f;
        const float vmp = (okm && olp) ? p[-IW + 1] : 0.f;
        const float v0m = olm ? p[-1] : 0.f;
        const float v00 = p[0];
        const float v0p = olp ? p[1] : 0.f;
        const float vpm = (okp && olm) ? p[IW - 1] : 0.f;
        const float vp0 = okp ? p[IW] : 0.f;
        const float vpp = (okp && olp) ? p[IW + 1] : 0.f;
        a00 = fmaf(v00, wp[1 * 4 + 1], a00);
        a00 = fmaf(v0m, wp[1 * 4 + 3], a00);
        a00 = fmaf(vm0, wp[3 * 4 + 1], a00);
        a00 = fmaf(vmm, wp[3 * 4 + 3], a00);
        a01 = fmaf(v0p, wp[1 * 4 + 0], a01);
        a01 = fmaf(v00, wp[1 * 4 + 2], a01);
        a01 = fmaf(vmp, wp[3 * 4 + 0], a01);
        a01 = fmaf(vm0, wp[3 * 4 + 2], a01);
        a10 = fmaf(vp0, wp[0 * 4 + 1], a10);
        a10 = fmaf(vpm, wp[0 * 4 + 3], a10);
        a10 = fmaf(v00, wp[2 * 4 + 1], a10);
        a10 = fmaf(v0m, wp[2 * 4 + 3], a10);
        a11 = fmaf(vpp, wp[0 * 4 + 0], a11);
        a11 = fmaf(vp0, wp[0 * 4 + 2], a11);
        a11 = fmaf(v0p, wp[2 * 4 + 0], a11);
        a11 = fmaf(v00, wp[2 * 4 + 2], a11);
    }

    float* __restrict__ outb = out + (size_t)b * 256 * 256;
    ((float2*)(outb + (size_t)(2 * i) * OW))[j] = make_float2(a00, a01);
    ((float2*)(outb + (size_t)(2 * i + 1) * OW))[j] = make_float2(a10, a11);
}

// Vector quantization (validated R5). Sequential dot chain — DO NOT change
// accumulation order (R3: 4-partial split flipped argmin).
__global__ __launch_bounds__(256) void vq_kernel(
    const float* __restrict__ h,   // (B,64,HW)
    const float* __restrict__ cb,  // (512,64)
    float* __restrict__ q,         // (B,64,HW)
    int B, int HW)
{
    __shared__ float ee[512];
    __shared__ __align__(16) float cbl[128 * 64];

    for (int k = threadIdx.x; k < 512; k += 256) {
        const float* __restrict__ cp = cb + (size_t)k * 64;
        float s = 0.0f;
#pragma unroll
        for (int i = 0; i < 64; i++) s = fmaf(cp[i], cp[i], s);
        ee[k] = s;
    }

    const int gid = blockIdx.x * 256 + threadIdx.x;  // grid exact: B*HW/256
    const int hw = gid % HW;
    const int b  = gid / HW;

    const float* __restrict__ hp = h + (size_t)b * 64 * HW + hw;
    float x[64];
#pragma unroll
    for (int i = 0; i < 64; i++) x[i] = hp[(size_t)i * HW];
    float xx = 0.0f;
#pragma unroll
    for (int i = 0; i < 64; i++) xx = fmaf(x[i], x[i], xx);

    float best = 3.402823466e+38f;
    int bidx = 0;
    for (int kc = 0; kc < 4; kc++) {
        __syncthreads();
        for (int idx = threadIdx.x; idx < 8192; idx += 256)
            cbl[idx] = cb[(size_t)kc * 8192 + idx];
        __syncthreads();
#pragma unroll 2
        for (int kl = 0; kl < 128; kl++) {
            const float* __restrict__ cp = cbl + kl * 64;
            float dot = 0.0f;
#pragma unroll
            for (int i = 0; i < 64; i++) dot = fmaf(x[i], cp[i], dot);
            const int k = kc * 128 + kl;
            const float d = xx - 2.0f * dot + ee[k];
            if (d < best) { best = d; bidx = k; }
        }
    }

    const float4* __restrict__ cp4 = (const float4*)(cb + (size_t)bidx * 64);
    float* __restrict__ qp = q + (size_t)b * 64 * HW + hw;
#pragma unroll
    for (int i = 0; i < 16; i++) {
        const float4 v = cp4[i];
        qp[(size_t)(4 * i + 0) * HW] = v.x;
        qp[(size_t)(4 * i + 1) * HW] = v.y;
        qp[(size_t)(4 * i + 2) * HW] = v.z;
        qp[(size_t)(4 * i + 3) * HW] = v.w;
    }
}

extern "C" void kernel_launch(void* const* d_in, const int* in_sizes, int n_in,
                              void* d_out, int out_size, void* d_ws, size_t ws_size,
                              hipStream_t stream) {
    const float* x      = (const float*)d_in[0];
    const float* w_e1   = (const float*)d_in[1];
    const float* b_e1   = (const float*)d_in[2];
    const float* w_e2   = (const float*)d_in[3];
    const float* b_e2   = (const float*)d_in[4];
    const float* w_er1a = (const float*)d_in[5];
    const float* w_er1b = (const float*)d_in[6];
    const float* w_er2a = (const float*)d_in[7];
    const float* w_er2b = (const float*)d_in[8];
    const float* w_pre  = (const float*)d_in[9];
    const float* b_pre  = (const float*)d_in[10];
    const float* cbk    = (const float*)d_in[11];
    const float* w_d1   = (const float*)d_in[12];
    const float* b_d1   = (const float*)d_in[13];
    const float* w_dr1a = (const float*)d_in[14];
    const float* w_dr1b = (const float*)d_in[15];
    const float* w_dr2a = (const float*)d_in[16];
    const float* w_dr2b = (const float*)d_in[17];
    const float* w_t1   = (const float*)d_in[18];
    const float* b_t1   = (const float*)d_in[19];
    const float* w_t2   = (const float*)d_in[20];
    const float* b_t2   = (const float*)d_in[21];
    float* out = (float*)d_out;

    float* A  = (float*)d_ws;            // (32,32,128,128) = 16777216
    float* Bb = A  + 16777216;           // (32,64,64,64)   = 8388608
    float* C  = Bb + 8388608;            // (32,32,64,64)   = 4194304
    float* D  = C  + 4194304;            // (32,64,64,64)   = 8388608
    float* WR = D  + 8388608;            // repacked weights

    float* r_e1   = WR;                  // 512
    float* r_e2   = r_e1  + 512;         // 32768
    float* r_er1a = r_e2  + 32768;       // 18432
    float* r_er1b = r_er1a + 18432;      // 2048
    float* r_er2a = r_er1b + 2048;       // 18432
    float* r_er2b = r_er2a + 18432;      // 2048
    float* r_pre  = r_er2b + 2048;       // 4096
    float* r_d1   = r_pre  + 4096;       // 36864
    float* r_dr1a = r_d1   + 36864;      // 18432
    float* r_dr1b = r_dr1a + 18432;      // 2048
    float* r_dr2a = r_dr1b + 2048;       // 18432
    float* r_dr2b = r_dr2a + 18432;      // 2048
    float* r_t1   = r_dr2b + 2048;       // 32768

    const dim3 blk(256);
    auto rb = [](int n) { return dim3((n + 255) / 256); };

    repack_w<<<rb(512),   blk, 0, stream>>>(w_e1,   r_e1,   32,  1, 16);
    repack_w<<<rb(32768), blk, 0, stream>>>(w_e2,   r_e2,   64, 32, 16);
    repack_w<<<rb(18432), blk, 0, stream>>>(w_er1a, r_er1a, 32, 64,  9);
    repack_w<<<rb(2048),  blk, 0, stream>>>(w_er1b, r_er1b, 64, 32,  1);
    repack_w<<<rb(18432), blk, 0, stream>>>(w_er2a, r_er2a, 32, 64,  9);
    repack_w<<<rb(2048),  blk, 0, stream>>>(w_er2b, r_er2b, 64, 32,  1);
    repack_w<<<rb(4096),  blk, 0, stream>>>(w_pre,  r_pre,  64, 64,  1);
    repack_w<<<rb(36864), blk, 0, stream>>>(w_d1,   r_d1,   64, 64,  9);
    repack_w<<<rb(18432), blk, 0, stream>>>(w_dr1a, r_dr1a, 32, 64,  9);
    repack_w<<<rb(2048),  blk, 0, stream>>>(w_dr1b, r_dr1b, 64, 32,  1);
    repack_w<<<rb(18432), blk, 0, stream>>>(w_dr2a, r_dr2a, 32, 64,  9);
    repack_w<<<rb(2048),  blk, 0, stream>>>(w_dr2b, r_dr2b, 64, 32,  1);
    repack_t1<<<rb(32768), blk, 0, stream>>>(w_t1, r_t1);

    // Encoder
    // e1: N = 32*128*128 = 524288 -> 2048 blocks
    conv_gemm<32, 8, 1, 4, 2, 1, false, true, false, true>
        <<<dim3(2048), blk, 0, stream>>>(x, r_e1, b_e1, nullptr, A,
                                         256, 256, 128, 128);
    // e2: N = 131072 -> 512 blocks
    conv_gemm<64, 16, 32, 4, 2, 1, false, true, false, false>
        <<<dim3(512), blk, 0, stream>>>(A, r_e2, b_e2, nullptr, Bb,
                                        128, 128, 64, 64);
    conv_gemm<32, 8, 64, 3, 1, 1, true, false, false, false>
        <<<dim3(512), blk, 0, stream>>>(Bb, r_er1a, nullptr, nullptr, C,
                                        64, 64, 64, 64);
    conv_gemm<64, 16, 32, 1, 1, 0, true, false, true, false>
        <<<dim3(512), blk, 0, stream>>>(C, r_er1b, nullptr, Bb, Bb,
                                        64, 64, 64, 64);
    conv_gemm<32, 8, 64, 3, 1, 1, true, false, false, false>
        <<<dim3(512), blk, 0, stream>>>(Bb, r_er2a, nullptr, nullptr, C,
                                        64, 64, 64, 64);
    conv_gemm<64, 16, 32, 1, 1, 0, true, false, true, false>
        <<<dim3(512), blk, 0, stream>>>(C, r_er2b, nullptr, Bb, Bb,
                                        64, 64, 64, 64);
    conv_gemm<64, 16, 64, 1, 1, 0, false, true, false, false>
        <<<dim3(512), blk, 0, stream>>>(Bb, r_pre, b_pre, nullptr, D,
                                        64, 64, 64, 64);
    // VQ
    vq_kernel<<<dim3(512), blk, 0, stream>>>(D, cbk, Bb, 32, 4096);
    // Decoder
    conv_gemm<64, 16, 64, 3, 1, 1, false, true, false, false>
        <<<dim3(512), blk, 0, stream>>>(Bb, r_d1, b_d1, nullptr, D,
                                        64, 64, 64, 64);
    conv_gemm<32, 8, 64, 3, 1, 1, true, false, false, false>
        <<<dim3(512), blk, 0, stream>>>(D, r_dr1a, nullptr, nullptr, C,
                                        64, 64, 64, 64);
    conv_gemm<64, 16, 32, 1, 1, 0, true, false, true, false>
        <<<dim3(512), blk, 0, stream>>>(C, r_dr1b, nullptr, D, D,
                                        64, 64, 64, 64);
    conv_gemm<32, 8, 64, 3, 1, 1, true, false, false, false>
        <<<dim3(512), blk, 0, stream>>>(D, r_dr2a, nullptr, nullptr, C,
                                        64, 64, 64, 64);
    conv_gemm<64, 16, 32, 1, 1, 0, true, false, true, false>
        <<<dim3(512), blk, 0, stream>>>(C, r_dr2b, nullptr, D, D,
                                        64, 64, 64, 64);
    // t1: N = 131072 -> 512 blocks x 4 parities
    convt_gemm<<<dim3(512, 4), blk, 0, stream>>>(D, r_t1, b_t1, A, 64, 64);
    // t2
    convt2_quad<<<dim3(64, 32), blk, 0, stream>>>(A, w_t2, b_t2, out, 32);
}

// Round 7
// 1629.722 us; speedup vs baseline: 1.4776x; 1.2274x over previous
//
#include <hip/hip_runtime.h>
#include <hip/hip_bf16.h>

// ---------------------------------------------------------------------------
// VQ-VAE forward, fp32. NCHW.
// R7: (a) VQ codebook via wave-uniform scalar loads (R6 was LDS-read-bound:
// 8192 ds_read_b128/thread ≈ 797k cyc/CU = measured 332us), 4 independent
// code-chains for issue saturation; per-code dot chain order UNCHANGED.
// (b) conv_gemm: ci-major staging w/ compile-time tap offsets (no div/mod),
// double-buffered LDS, 1 barrier/chunk. Per-output FMA order everywhere is
// (ci asc, kk asc) with bias init — bit-identical to R4/R6 (R3 lesson: VQ
// argmin flips on 1-ulp changes upstream).
// ---------------------------------------------------------------------------

// dst[(ci*KK+kk)*COUT+co] = src[(co*CIN+ci)*KK+kk]
__global__ __launch_bounds__(256) void repack_w(
    const float* __restrict__ src, float* __restrict__ dst,
    int COUT, int CIN, int KK)
{
    const int n = COUT * CIN * KK;
    const int idx = blockIdx.x * 256 + threadIdx.x;
    if (idx >= n) return;
    const int co = idx % COUT;
    const int t  = idx / COUT;
    const int kk = t % KK;
    const int ci = t / KK;
    dst[idx] = src[(co * CIN + ci) * KK + kk];
}

// t1 weights (64,32,4,4) [ci][co][kh][kw] -> dst[par][ci*4+tap][co]
__global__ __launch_bounds__(256) void repack_t1(
    const float* __restrict__ src, float* __restrict__ dst)
{
    const int idx = blockIdx.x * 256 + threadIdx.x;
    if (idx >= 32768) return;
    const int co  = idx & 31;
    const int tap = (idx >> 5) & 3;
    const int ci  = (idx >> 7) & 63;
    const int par = idx >> 13;
    const int pr = par >> 1, pc = par & 1;
    const int ta = tap >> 1, tb = tap & 1;
    const int kh = (1 - pr) + 2 * ta, kw = (1 - pc) + 2 * tb;
    dst[idx] = src[((ci * 32 + co) * 4 + kh) * 4 + kw];
}

// GEMM-form conv. Block: CTOT couts x 256 pixels; thread: CPTHD x 4 pixels.
// K-chunks = CIC cis x KK taps (compile-time kk), double-buffered LDS.
template<int CTOT, int CPTHD, int CIN, int K, int S, int PAD,
         bool RELU_IN, bool HAS_BIAS, bool RESID, bool RELU_OUT>
__global__ __launch_bounds__(256) void conv_gemm(
    const float* __restrict__ in, const float* __restrict__ wr,
    const float* __restrict__ bias, const float* __restrict__ resid,
    float* __restrict__ out,
    int H, int W, int OH, int OW)
{
    constexpr int KK  = K * K;
    constexpr int CIC = (K == 1) ? 8 : 1;     // cis per chunk
    constexpr int KC  = CIC * KK;             // k-steps per chunk (8, 9, 16)
    constexpr int NCH = CIN / CIC;
    constexpr int NT  = 256;
    __shared__ __align__(16) float As[2][KC * NT];

    const int tid = threadIdx.x;
    const int tpx = tid & 63;
    const int tco = __builtin_amdgcn_readfirstlane(tid >> 6);
    const int co0 = tco * CPTHD;

    const int ohow = OH * OW;
    const int n_st = blockIdx.x * NT + tid;
    const int b_st = n_st / ohow;
    const int hw_s = n_st % ohow;
    const int ih0 = (hw_s / OW) * S - PAD;
    const int iw0 = (hw_s % OW) * S - PAD;
    const float* __restrict__ inb = in + (size_t)b_st * CIN * H * W;

    float acc[CPTHD][4];
#pragma unroll
    for (int c = 0; c < CPTHD; c++) {
        const float bz = HAS_BIAS ? bias[co0 + c] : 0.0f;
#pragma unroll
        for (int q = 0; q < 4; q++) acc[c][q] = bz;
    }

    float pf[KC];
    auto stage_load = [&](int ci0) {
#pragma unroll
        for (int cc = 0; cc < CIC; cc++) {
            const float* __restrict__ inc = inb + (size_t)(ci0 + cc) * H * W;
#pragma unroll
            for (int kk = 0; kk < KK; kk++) {
                const int kh = kk / K, kw = kk % K;   // compile-time
                const int ih = ih0 + kh, iw = iw0 + kw;
                float v = 0.0f;
                if (ih >= 0 && ih < H && iw >= 0 && iw < W)
                    v = inc[ih * W + iw];
                if (RELU_IN) v = fmaxf(v, 0.0f);
                pf[cc * KK + kk] = v;
            }
        }
    };

    stage_load(0);
#pragma unroll
    for (int t = 0; t < KC; t++) As[0][t * NT + tid] = pf[t];
    __syncthreads();

#pragma unroll 2
    for (int c = 0; c < NCH; c++) {
        const int cur = c & 1;
        if (c + 1 < NCH) stage_load((c + 1) * CIC);

#pragma unroll
        for (int t = 0; t < KC; t++) {
            const float4 a4 = *(const float4*)(As[cur] + t * NT + tpx * 4);
            const float* __restrict__ wk =
                wr + (size_t)(c * KC + t) * CTOT + co0;
#pragma unroll
            for (int cc = 0; cc < CPTHD; cc++) {
                const float w = wk[cc];
                acc[cc][0] = fmaf(a4.x, w, acc[cc][0]);
                acc[cc][1] = fmaf(a4.y, w, acc[cc][1]);
                acc[cc][2] = fmaf(a4.z, w, acc[cc][2]);
                acc[cc][3] = fmaf(a4.w, w, acc[cc][3]);
            }
        }

        if (c + 1 < NCH) {
#pragma unroll
            for (int t = 0; t < KC; t++) As[1 - cur][t * NT + tid] = pf[t];
        }
        __syncthreads();
    }

    const int n_c  = blockIdx.x * NT + tpx * 4;
    const int b_c  = n_c / ohow;
    const int hw_c = n_c % ohow;
    float* __restrict__ op = out + (size_t)b_c * CTOT * ohow + hw_c;
    const float* __restrict__ rp =
        RESID ? (resid + (size_t)b_c * CTOT * ohow + hw_c) : nullptr;
#pragma unroll
    for (int c = 0; c < CPTHD; c++) {
        const size_t off = (size_t)(co0 + c) * ohow;
        float4 r = make_float4(acc[c][0], acc[c][1], acc[c][2], acc[c][3]);
        if (RESID) {
            const float4 rv = *(const float4*)(rp + off);
            r.x += rv.x; r.y += rv.y; r.z += rv.z; r.w += rv.w;
        }
        if (RELU_OUT) {
            r.x = fmaxf(r.x, 0.f); r.y = fmaxf(r.y, 0.f);
            r.z = fmaxf(r.z, 0.f); r.w = fmaxf(r.w, 0.f);
        }
        *(float4*)(op + off) = r;
    }
}

// GEMM-form transposed conv t1 (64 -> 32, 4x4 s2 p1), per parity class.
__global__ __launch_bounds__(256) void convt_gemm(
    const float* __restrict__ in, const float* __restrict__ wr,  // [par][256][32]
    const float* __restrict__ bias, float* __restrict__ out,
    int IH, int IW)
{
    constexpr int NT = 256, KC = 8, KTOT = 256, CTOT = 32, CPTHD = 8;
    __shared__ __align__(16) float As[KC * NT];

    const int tid = threadIdx.x;
    const int tpx = tid & 63;
    const int tco = __builtin_amdgcn_readfirstlane(tid >> 6);
    const int co0 = tco * CPTHD;
    const int par = blockIdx.y;
    const int pr = par >> 1, pc = par & 1;
    const int ihiw = IH * IW;
    const int OH = IH * 2, OW = IW * 2;

    const int n_st = blockIdx.x * NT + tid;
    const int b_st = n_st / ihiw;
    const int r_s  = n_st % ihiw;
    const int i_st = r_s / IW;
    const int j_st = r_s % IW;
    const float* __restrict__ inb = in + (size_t)b_st * 64 * ihiw;

    float acc[CPTHD][4];
#pragma unroll
    for (int c = 0; c < CPTHD; c++) {
        const float bz = bias[co0 + c];
#pragma unroll
        for (int q = 0; q < 4; q++) acc[c][q] = bz;
    }

    const float* __restrict__ wpar = wr + (size_t)par * KTOT * CTOT;

#pragma unroll 1
    for (int k0 = 0; k0 < KTOT; k0 += KC) {
        __syncthreads();
#pragma unroll
        for (int t = 0; t < KC; t++) {
            const int k  = k0 + t;
            const int ci = k >> 2;
            const int ta = (k >> 1) & 1;
            const int tb = k & 1;
            const int ih = i_st + pr - ta;
            const int iw = j_st + pc - tb;
            float v = 0.0f;
            if (ih >= 0 && ih < IH && iw >= 0 && iw < IW)
                v = inb[(size_t)ci * ihiw + ih * IW + iw];
            As[t * NT + tid] = v;
        }
        __syncthreads();
#pragma unroll
        for (int t = 0; t < KC; t++) {
            const float4 a4 = *(const float4*)(As + t * NT + tpx * 4);
            const float* __restrict__ wk = wpar + (size_t)(k0 + t) * CTOT + co0;
#pragma unroll
            for (int c = 0; c < CPTHD; c++) {
                const float w = wk[c];
                acc[c][0] = fmaf(a4.x, w, acc[c][0]);
                acc[c][1] = fmaf(a4.y, w, acc[c][1]);
                acc[c][2] = fmaf(a4.z, w, acc[c][2]);
                acc[c][3] = fmaf(a4.w, w, acc[c][3]);
            }
        }
    }

    const int n_c = blockIdx.x * NT + tpx * 4;
    const int b_c = n_c / ihiw;
    const int r_c = n_c % ihiw;
    const int i_c = r_c / IW;
    const int j_c = r_c % IW;
    const int oh = 2 * i_c + pr;
    float* __restrict__ ob = out + (size_t)b_c * CTOT * OH * OW + (size_t)oh * OW;
#pragma unroll
    for (int c = 0; c < CPTHD; c++) {
        const size_t off = (size_t)(co0 + c) * OH * OW;
#pragma unroll
        for (int q = 0; q < 4; q++)
            ob[off + 2 * (j_c + q) + pc] = fmaxf(acc[c][q], 0.0f);
    }
}

// Final transposed conv (32 -> 1): one thread per half-res position computes
// the 2x2 output quad from its 3x3 neighborhood. (validated)
__global__ __launch_bounds__(256) void convt2_quad(
    const float* __restrict__ in,  // (B,32,128,128)
    const float* __restrict__ w,   // (32,1,4,4)
    const float* __restrict__ bias,
    float* __restrict__ out,       // (B,1,256,256)
    int B)
{
    const int IH = 128, IW = 128, CIN = 32, OW = 256;
    const int j = threadIdx.x & 127;
    const int i = (blockIdx.x << 1) + (threadIdx.x >> 7);
    const int b = blockIdx.y;

    const float* __restrict__ inb = in + (size_t)b * CIN * IH * IW;
    const float bz = bias[0];
    float a00 = bz, a01 = bz, a10 = bz, a11 = bz;

    const bool okm = (i > 0);
    const bool okp = (i < IH - 1);
    const bool olm = (j > 0);
    const bool olp = (j < IW - 1);

#pragma unroll 4
    for (int ci = 0; ci < CIN; ci++) {
        const float* __restrict__ p = inb + ((size_t)ci * IH + i) * IW + j;
        const float* __restrict__ wp = w + ci * 16;
        const float vmm = (okm && olm) ? p[-IW - 1] : 0.f;
        const float vm0 = okm ? p[-IW] : 0.f;
        const float vmp = (okm && olp) ? p[-IW + 1] : 0.f;
        const float v0m = olm ? p[-1] : 0.f;
        const float v00 = p[0];
        const float v0p = olp ? p[1] : 0.f;
        const float vpm = (okp && olm) ? p[IW - 1] : 0.f;
        const float vp0 = okp ? p[IW] : 0.f;
        const float vpp = (okp && olp) ? p[IW + 1] : 0.f;
        a00 = fmaf(v00, wp[1 * 4 + 1], a00);
        a00 = fmaf(v0m, wp[1 * 4 + 3], a00);
        a00 = fmaf(vm0, wp[3 * 4 + 1], a00);
        a00 = fmaf(vmm, wp[3 * 4 + 3], a00);
        a01 = fmaf(v0p, wp[1 * 4 + 0], a01);
        a01 = fmaf(v00, wp[1 * 4 + 2], a01);
        a01 = fmaf(vmp, wp[3 * 4 + 0], a01);
        a01 = fmaf(vm0, wp[3 * 4 + 2], a01);
        a10 = fmaf(vp0, wp[0 * 4 + 1], a10);
        a10 = fmaf(vpm, wp[0 * 4 + 3], a10);
        a10 = fmaf(v00, wp[2 * 4 + 1], a10);
        a10 = fmaf(v0m, wp[2 * 4 + 3], a10);
        a11 = fmaf(vpp, wp[0 * 4 + 0], a11);
        a11 = fmaf(vp0, wp[0 * 4 + 2], a11);
        a11 = fmaf(v0p, wp[2 * 4 + 0], a11);
        a11 = fmaf(v00, wp[2 * 4 + 2], a11);
    }

    float* __restrict__ outb = out + (size_t)b * 256 * 256;
    ((float2*)(outb + (size_t)(2 * i) * OW))[j] = make_float2(a00, a01);
    ((float2*)(outb + (size_t)(2 * i + 1) * OW))[j] = make_float2(a10, a11);
}

// Vector quantization. Codebook rows read via wave-uniform scalar loads (no
// LDS in the hot loop); 4 independent code chains per iteration. Per-code
// dot chain is the SAME sequential FMA order; compares ascend in k with
// strict < — argmin bit-identical. DO NOT split the per-code chain (R3).
__global__ __launch_bounds__(256) void vq_kernel(
    const float* __restrict__ h,   // (B,64,HW)
    const float* __restrict__ cb,  // (512,64)
    float* __restrict__ q,         // (B,64,HW)
    int B, int HW)
{
    __shared__ float ee[512];
    for (int k = threadIdx.x; k < 512; k += 256) {
        const float* __restrict__ cp = cb + (size_t)k * 64;
        float s = 0.0f;
#pragma unroll
        for (int i = 0; i < 64; i++) s = fmaf(cp[i], cp[i], s);
        ee[k] = s;
    }
    __syncthreads();

    const int gid = blockIdx.x * 256 + threadIdx.x;  // grid exact: B*HW/256
    const int hw = gid % HW;
    const int b  = gid / HW;

    const float* __restrict__ hp = h + (size_t)b * 64 * HW + hw;
    float x[64];
#pragma unroll
    for (int i = 0; i < 64; i++) x[i] = hp[(size_t)i * HW];
    float xx = 0.0f;
#pragma unroll
    for (int i = 0; i < 64; i++) xx = fmaf(x[i], x[i], xx);

    float best = 3.402823466e+38f;
    int bidx = 0;
#pragma unroll 1
    for (int k0 = 0; k0 < 512; k0 += 4) {
        float d[4];
#pragma unroll
        for (int u = 0; u < 4; u++) {
            const float* __restrict__ cp =
                cb + (size_t)__builtin_amdgcn_readfirstlane((k0 + u) << 6);
            float dot = 0.0f;
#pragma unroll
            for (int i = 0; i < 64; i++) dot = fmaf(x[i], cp[i], dot);
            d[u] = xx - 2.0f * dot + ee[k0 + u];
        }
#pragma unroll
        for (int u = 0; u < 4; u++)
            if (d[u] < best) { best = d[u]; bidx = k0 + u; }
    }

    const float4* __restrict__ cp4 = (const float4*)(cb + (size_t)bidx * 64);
    float* __restrict__ qp = q + (size_t)b * 64 * HW + hw;
#pragma unroll
    for (int i = 0; i < 16; i++) {
        const float4 v = cp4[i];
        qp[(size_t)(4 * i + 0) * HW] = v.x;
        qp[(size_t)(4 * i + 1) * HW] = v.y;
        qp[(size_t)(4 * i + 2) * HW] = v.z;
        qp[(size_t)(4 * i + 3) * HW] = v.w;
    }
}

extern "C" void kernel_launch(void* const* d_in, const int* in_sizes, int n_in,
                              void* d_out, int out_size, void* d_ws, size_t ws_size,
                              hipStream_t stream) {
    const float* x      = (const float*)d_in[0];
    const float* w_e1   = (const float*)d_in[1];
    const float* b_e1   = (const float*)d_in[2];
    const float* w_e2   = (const float*)d_in[3];
    const float* b_e2   = (const float*)d_in[4];
    const float* w_er1a = (const float*)d_in[5];
    const float* w_er1b = (const float*)d_in[6];
    const float* w_er2a = (const float*)d_in[7];
    const float* w_er2b = (const float*)d_in[8];
    const float* w_pre  = (const float*)d_in[9];
    const float* b_pre  = (const float*)d_in[10];
    const float* cbk    = (const float*)d_in[11];
    const float* w_d1   = (const float*)d_in[12];
    const float* b_d1   = (const float*)d_in[13];
    const float* w_dr1a = (const float*)d_in[14];
    const float* w_dr1b = (const float*)d_in[15];
    const float* w_dr2a = (const float*)d_in[16];
    const float* w_dr2b = (const float*)d_in[17];
    const float* w_t1   = (const float*)d_in[18];
    const float* b_t1   = (const float*)d_in[19];
    const float* w_t2   = (const float*)d_in[20];
    const float* b_t2   = (const float*)d_in[21];
    float* out = (float*)d_out;

    float* A  = (float*)d_ws;            // (32,32,128,128) = 16777216
    float* Bb = A  + 16777216;           // (32,64,64,64)   = 8388608
    float* C  = Bb + 8388608;            // (32,32,64,64)   = 4194304
    float* D  = C  + 4194304;            // (32,64,64,64)   = 8388608
    float* WR = D  + 8388608;            // repacked weights

    float* r_e1   = WR;                  // 512
    float* r_e2   = r_e1  + 512;         // 32768
    float* r_er1a = r_e2  + 32768;       // 18432
    float* r_er1b = r_er1a + 18432;      // 2048
    float* r_er2a = r_er1b + 2048;       // 18432
    float* r_er2b = r_er2a + 18432;      // 2048
    float* r_pre  = r_er2b + 2048;       // 4096
    float* r_d1   = r_pre  + 4096;       // 36864
    float* r_dr1a = r_d1   + 36864;      // 18432
    float* r_dr1b = r_dr1a + 18432;      // 2048
    float* r_dr2a = r_dr1b + 2048;       // 18432
    float* r_dr2b = r_dr2a + 18432;      // 2048
    float* r_t1   = r_dr2b + 2048;       // 32768

    const dim3 blk(256);
    auto rb = [](int n) { return dim3((n + 255) / 256); };

    repack_w<<<rb(512),   blk, 0, stream>>>(w_e1,   r_e1,   32,  1, 16);
    repack_w<<<rb(32768), blk, 0, stream>>>(w_e2,   r_e2,   64, 32, 16);
    repack_w<<<rb(18432), blk, 0, stream>>>(w_er1a, r_er1a, 32, 64,  9);
    repack_w<<<rb(2048),  blk, 0, stream>>>(w_er1b, r_er1b, 64, 32,  1);
    repack_w<<<rb(18432), blk, 0, stream>>>(w_er2a, r_er2a, 32, 64,  9);
    repack_w<<<rb(2048),  blk, 0, stream>>>(w_er2b, r_er2b, 64, 32,  1);
    repack_w<<<rb(4096),  blk, 0, stream>>>(w_pre,  r_pre,  64, 64,  1);
    repack_w<<<rb(36864), blk, 0, stream>>>(w_d1,   r_d1,   64, 64,  9);
    repack_w<<<rb(18432), blk, 0, stream>>>(w_dr1a, r_dr1a, 32, 64,  9);
    repack_w<<<rb(2048),  blk, 0, stream>>>(w_dr1b, r_dr1b, 64, 32,  1);
    repack_w<<<rb(18432), blk, 0, stream>>>(w_dr2a, r_dr2a, 32, 64,  9);
    repack_w<<<rb(2048),  blk, 0, stream>>>(w_dr2b, r_dr2b, 64, 32,  1);
    repack_t1<<<rb(32768), blk, 0, stream>>>(w_t1, r_t1);

    // Encoder
    conv_gemm<32, 8, 1, 4, 2, 1, false, true, false, true>
        <<<dim3(2048), blk, 0, stream>>>(x, r_e1, b_e1, nullptr, A,
                                         256, 256, 128, 128);
    conv_gemm<64, 16, 32, 4, 2, 1, false, true, false, false>
        <<<dim3(512), blk, 0, stream>>>(A, r_e2, b_e2, nullptr, Bb,
                                        128, 128, 64, 64);
    conv_gemm<32, 8, 64, 3, 1, 1, true, false, false, false>
        <<<dim3(512), blk, 0, stream>>>(Bb, r_er1a, nullptr, nullptr, C,
                                        64, 64, 64, 64);
    conv_gemm<64, 16, 32, 1, 1, 0, true, false, true, false>
        <<<dim3(512), blk, 0, stream>>>(C, r_er1b, nullptr, Bb, Bb,
                                        64, 64, 64, 64);
    conv_gemm<32, 8, 64, 3, 1, 1, true, false, false, false>
        <<<dim3(512), blk, 0, stream>>>(Bb, r_er2a, nullptr, nullptr, C,
                                        64, 64, 64, 64);
    conv_gemm<64, 16, 32, 1, 1, 0, true, false, true, false>
        <<<dim3(512), blk, 0, stream>>>(C, r_er2b, nullptr, Bb, Bb,
                                        64, 64, 64, 64);
    conv_gemm<64, 16, 64, 1, 1, 0, false, true, false, false>
        <<<dim3(512), blk, 0, stream>>>(Bb, r_pre, b_pre, nullptr, D,
                                        64, 64, 64, 64);
    // VQ
    vq_kernel<<<dim3(512), blk, 0, stream>>>(D, cbk, Bb, 32, 4096);
    // Decoder
    conv_gemm<64, 16, 64, 3, 1, 1, false, true, false, false>
        <<<dim3(512), blk, 0, stream>>>(Bb, r_d1, b_d1, nullptr, D,
                                        64, 64, 64, 64);
    conv_gemm<32, 8, 64, 3, 1, 1, true, false, false, false>
        <<<dim3(512), blk, 0, stream>>>(D, r_dr1a, nullptr, nullptr, C,
                                        64, 64, 64, 64);
    conv_gemm<64, 16, 32, 1, 1, 0, true, false, true, false>
        <<<dim3(512), blk, 0, stream>>>(C, r_dr1b, nullptr, D, D,
                                        64, 64, 64, 64);
    conv_gemm<32, 8, 64, 3, 1, 1, true, false, false, false>
        <<<dim3(512), blk, 0, stream>>>(D, r_dr2a, nullptr, nullptr, C,
                                        64, 64, 64, 64);
    conv_gemm<64, 16, 32, 1, 1, 0, true, false, true, false>
        <<<dim3(512), blk, 0, stream>>>(C, r_dr2b, nullptr, D, D,
                                        64, 64, 64, 64);
    // t1
    convt_gemm<<<dim3(512, 4), blk, 0, stream>>>(D, r_t1, b_t1, A, 64, 64);
    // t2
    convt2_quad<<<dim3(64, 32), blk, 0, stream>>>(A, w_t2, b_t2, out, 32);
}